// Round 1
// baseline (385.531 us; speedup 1.0000x reference)
//
#include <hip/hip_runtime.h>

#define NB 524288
#define ND 64
#define NH 19

__device__ __forceinline__ float fast_tanh(float x) {
    // tanh(x) = 1 - 2/(e^{2x}+1); clamp so e^{2x} stays finite.
    x = fminf(9.0f, fmaxf(-9.0f, x));
    float e = __expf(2.0f * x);               // v_exp_f32 path
    return 1.0f - 2.0f * __builtin_amdgcn_rcpf(e + 1.0f);  // v_rcp_f32 (~1 ulp)
}

// Kernel A: fused |x| partial reduction + mapped = x @ Wi^T + bi.
// mapped stored column-major [NH][NB] for coalesced store here / load in B.
extern "C" __global__ void __launch_bounds__(256)
ltc_mapped_urgency(const float* __restrict__ x, const float* __restrict__ Wi,
                   const float* __restrict__ bi, float* __restrict__ mapped,
                   double* __restrict__ acc, int storeMapped)
{
    const int b = blockIdx.x * 256 + threadIdx.x;
    const float4* xr = (const float4*)(x + (size_t)b * ND);
    float m[NH];
#pragma unroll
    for (int j = 0; j < NH; ++j) m[j] = bi[j];
    float s = 0.f;
#pragma unroll
    for (int q = 0; q < ND / 4; ++q) {
        const float4 v = xr[q];
        s += fabsf(v.x) + fabsf(v.y) + fabsf(v.z) + fabsf(v.w);
#pragma unroll
        for (int j = 0; j < NH; ++j) {
            // Wi indices are wave-uniform constants -> s_load + v_fmac(sgpr)
            m[j] = fmaf(v.x, Wi[j * ND + 4 * q + 0], m[j]);
            m[j] = fmaf(v.y, Wi[j * ND + 4 * q + 1], m[j]);
            m[j] = fmaf(v.z, Wi[j * ND + 4 * q + 2], m[j]);
            m[j] = fmaf(v.w, Wi[j * ND + 4 * q + 3], m[j]);
        }
    }
    if (storeMapped) {
#pragma unroll
        for (int j = 0; j < NH; ++j) mapped[(size_t)j * NB + b] = m[j];
    }
    // wave64 shuffle reduction, then 4-wave LDS combine, one double atomic/block
#pragma unroll
    for (int off = 32; off > 0; off >>= 1) s += __shfl_down(s, off, 64);
    __shared__ float red[4];
    const int lane = threadIdx.x & 63, w = threadIdx.x >> 6;
    if (lane == 0) red[w] = s;
    __syncthreads();
    if (threadIdx.x == 0) atomicAdd(acc, (double)(red[0] + red[1] + red[2] + red[3]));
}

// Kernel B: per-thread recurrence over ROWS rows (rows split gid, gid+T for
// coalesced mapped loads), 10 steps in registers, epilogue h@Wo^T + h writes.
template <bool RECOMP, int ROWS>
__global__ void __launch_bounds__(256)
ltc_steps(const float* __restrict__ x, const float* __restrict__ Wi,
          const float* __restrict__ bi, const float* __restrict__ mapped,
          const double* __restrict__ acc,
          const float* __restrict__ Wr, const float* __restrict__ Wo,
          const float* __restrict__ bo, const float* __restrict__ tau,
          const float* __restrict__ ta, const int* __restrict__ steps_p,
          float* __restrict__ out)
{
    const int gid = blockIdx.x * 256 + threadIdx.x;
    const int T = NB / ROWS;
    const double mean = *acc * (1.0 / ((double)NB * (double)ND));
    const float u = fmaxf((float)mean, 0.01f);
    float rr_[NH];  // dt / tau_dyn
#pragma unroll
    for (int j = 0; j < NH; ++j) {
        float t = tau[j] * (1.f - ta[j]) + ta[j] / u;
        t = fminf(10.f, fmaxf(0.01f, t));
        rr_[j] = 0.01f / t;
    }
    float m[ROWS][NH], h[ROWS][NH];
#pragma unroll
    for (int rI = 0; rI < ROWS; ++rI) {
        const int b = gid + rI * T;
        if (RECOMP) {
            const float4* xr = (const float4*)(x + (size_t)b * ND);
#pragma unroll
            for (int j = 0; j < NH; ++j) m[rI][j] = bi[j];
#pragma unroll
            for (int q = 0; q < ND / 4; ++q) {
                const float4 v = xr[q];
#pragma unroll
                for (int j = 0; j < NH; ++j) {
                    m[rI][j] = fmaf(v.x, Wi[j * ND + 4 * q + 0], m[rI][j]);
                    m[rI][j] = fmaf(v.y, Wi[j * ND + 4 * q + 1], m[rI][j]);
                    m[rI][j] = fmaf(v.z, Wi[j * ND + 4 * q + 2], m[rI][j]);
                    m[rI][j] = fmaf(v.w, Wi[j * ND + 4 * q + 3], m[rI][j]);
                }
            }
        } else {
#pragma unroll
            for (int j = 0; j < NH; ++j) m[rI][j] = mapped[(size_t)j * NB + b];
        }
#pragma unroll
        for (int j = 0; j < NH; ++j) h[rI][j] = 0.f;
    }
    const int steps = *steps_p;
    for (int s = 0; s < steps; ++s) {
#pragma unroll
        for (int rI = 0; rI < ROWS; ++rI) {
            float a[NH];
#pragma unroll
            for (int j = 0; j < NH; ++j) {
                float p = m[rI][j];
#pragma unroll
                for (int k = 0; k < NH; ++k)
                    p = fmaf(h[rI][k], Wr[j * NH + k], p);  // Wr via s_load
                a[j] = fast_tanh(p);
            }
#pragma unroll
            for (int j = 0; j < NH; ++j) h[rI][j] += rr_[j] * (a[j] - h[rI][j]);
        }
    }
#pragma unroll
    for (int rI = 0; rI < ROWS; ++rI) {
        const int b = gid + rI * T;
#pragma unroll
        for (int j = 0; j < NH; ++j) {
            float p = bo[j];
#pragma unroll
            for (int k = 0; k < NH; ++k) p = fmaf(h[rI][k], Wo[j * NH + k], p);
            out[(size_t)b * NH + j] = p;
        }
#pragma unroll
        for (int j = 0; j < NH; ++j)
            out[(size_t)NB * NH + (size_t)b * NH + j] = h[rI][j];
    }
}

extern "C" void kernel_launch(void* const* d_in, const int* in_sizes, int n_in,
                              void* d_out, int out_size, void* d_ws, size_t ws_size,
                              hipStream_t stream)
{
    const float* x   = (const float*)d_in[0];
    const float* Wi  = (const float*)d_in[1];
    const float* bi  = (const float*)d_in[2];
    const float* Wr  = (const float*)d_in[3];
    const float* Wo  = (const float*)d_in[4];
    const float* bo  = (const float*)d_in[5];
    const float* tau = (const float*)d_in[6];
    const float* ta  = (const float*)d_in[7];
    const int* steps = (const int*)d_in[8];
    float* out = (float*)d_out;

    double* acc = (double*)d_ws;
    float* mapped = (float*)((char*)d_ws + 16);
    const size_t need = 16 + (size_t)NB * NH * sizeof(float);
    const int storeMapped = (ws_size >= need) ? 1 : 0;

    hipMemsetAsync(d_ws, 0, sizeof(double), stream);  // ws re-poisoned each call
    ltc_mapped_urgency<<<NB / 256, 256, 0, stream>>>(x, Wi, bi, mapped, acc, storeMapped);

    constexpr int ROWS = 2;
    if (storeMapped)
        ltc_steps<false, ROWS><<<NB / ROWS / 256, 256, 0, stream>>>(
            x, Wi, bi, mapped, acc, Wr, Wo, bo, tau, ta, steps, out);
    else
        ltc_steps<true, ROWS><<<NB / ROWS / 256, 256, 0, stream>>>(
            x, Wi, bi, mapped, acc, Wr, Wo, bo, tau, ta, steps, out);
}